// Round 10
// baseline (83.825 us; speedup 1.0000x reference)
//
#include <hip/hip_runtime.h>
#include <hip/hip_bf16.h>

// Problem constants
#define BB 32
#define SS 256
#define DD 300
#define PDD 32
#define MM 66
#define FF 398      // D + PD + M
#define HH 6
#define G4 24       // 4*H
#define AA 12
#define L2E 1.4426950408889634f

__device__ __forceinline__ float fast_rcp(float x) { return __builtin_amdgcn_rcpf(x); }
__device__ __forceinline__ float fast_tanh(float x) {
    return 1.f - 2.f * fast_rcp(__expf(2.f * x) + 1.f);
}
__device__ __forceinline__ float bcast_lane(float x, int l) {
    return __int_as_float(__builtin_amdgcn_readlane(__float_as_int(x), l));
}
template<int CTRL>
__device__ __forceinline__ float quad_bcast(float v) {
    return __int_as_float(__builtin_amdgcn_mov_dpp(__float_as_int(v), CTRL, 0xf, 0xf, true));
}

// -------------------------------------------------------------------------
// Kernel 0: transpose Wx into WT[dir][j][400] (k-contiguous, zero-padded)
// so the GEMM can fetch W columns with uniform scalar loads. Tiny.
// -------------------------------------------------------------------------
__global__ __launch_bounds__(256) void k_wtprep(
    const float* __restrict__ Wxf, const float* __restrict__ Wxb,
    float* __restrict__ WT)
{
    const float* Wx = blockIdx.x ? Wxb : Wxf;
    float* wt = WT + blockIdx.x * (G4 * 400);
    for (int idx = threadIdx.x; idx < G4 * 400; idx += 256) {
        int j = idx / 400, k = idx % 400;
        wt[idx] = (k < FF) ? Wx[k * G4 + j] : 0.f;
    }
}

// -------------------------------------------------------------------------
// Kernel 1 (v6): xg partial GEMM, split-K.
// Grid = 128 pos-groups x 2 k-halves; block = 512 thr = 8 waves.
// Wave w owns col-group cg=w (wave-UNIFORM -> W loads become s_load via
// scalar pipe, zero LDS/VALU cost); lane = one of 64 positions.
// Feats k-half staged transposed in LDS: hot loop = 1 ds_read_b128 +
// 24 fma (SGPR W operand) per q. Partial sums -> xgp[kh]; bias/prescale
// folded into k_lstm staging.
// -------------------------------------------------------------------------
__global__ __launch_bounds__(512) void k_xg(
    const int* __restrict__ words, const int* __restrict__ pos,
    const float* __restrict__ morph, const float* __restrict__ wtab,
    const float* __restrict__ ptab, const float* __restrict__ WT,
    float* __restrict__ xgp0, float* __restrict__ xgp1)
{
    __shared__ float4 sF[50][66];        // 52.8 KB: sF[q][p] = feats[p][kh*200+4q ..+3]
    int t  = threadIdx.x;
    int kh = blockIdx.x & 1;
    int p0 = (blockIdx.x >> 1) * 64;

    if (kh == 0) {
        // k 0..199: pure word table
        for (int idx = t; idx < 64 * 50; idx += 512) {
            int p = idx / 50, q = idx % 50;
            sF[q][p] = *(const float4*)(wtab + (size_t)words[p0 + p] * DD + 4 * q);
        }
    } else {
        // k 200..299: word
        for (int idx = t; idx < 64 * 25; idx += 512) {
            int p = idx / 25, q = idx % 25;
            sF[q][p] = *(const float4*)(wtab + (size_t)words[p0 + p] * DD + 200 + 4 * q);
        }
        // k 300..331: pos table (q 25..32)
        for (int idx = t; idx < 64 * 8; idx += 512) {
            int p = idx / 8, q = idx % 8;
            sF[25 + q][p] = *(const float4*)(ptab + pos[p0 + p] * PDD + 4 * q);
        }
        // k 332..399: morph (66) + zero pad (2), float2 granularity (q 33..49)
        for (int idx = t; idx < 64 * 34; idx += 512) {
            int p = idx / 34, m = idx % 34;
            const float2* ms = (const float2*)(morph + (size_t)(p0 + p) * MM);
            float2 v = (m < 33) ? ms[m] : make_float2(0.f, 0.f);
            *(float2*)((float*)&sF[33 + (m >> 1)][p] + 2 * (m & 1)) = v;
        }
    }
    __syncthreads();

    int lane = t & 63;
    int cg   = __builtin_amdgcn_readfirstlane(t >> 6);   // 0..7, wave-uniform
    int dir  = cg >> 2;
    int j0   = (cg & 3) * 6;
    const float* wb = WT + (dir * G4 + j0) * 400 + kh * 200;

    float a0 = 0.f, a1 = 0.f, a2 = 0.f, a3 = 0.f, a4 = 0.f, a5 = 0.f;
    #pragma unroll 2
    for (int q = 0; q < 50; ++q) {
        float4 f  = sF[q][lane];
        float4 w0 = *(const float4*)(wb + 0 * 400 + 4 * q);
        float4 w1 = *(const float4*)(wb + 1 * 400 + 4 * q);
        float4 w2 = *(const float4*)(wb + 2 * 400 + 4 * q);
        float4 w3 = *(const float4*)(wb + 3 * 400 + 4 * q);
        float4 w4 = *(const float4*)(wb + 4 * 400 + 4 * q);
        float4 w5 = *(const float4*)(wb + 5 * 400 + 4 * q);
        a0 = fmaf(f.x, w0.x, a0); a0 = fmaf(f.y, w0.y, a0);
        a0 = fmaf(f.z, w0.z, a0); a0 = fmaf(f.w, w0.w, a0);
        a1 = fmaf(f.x, w1.x, a1); a1 = fmaf(f.y, w1.y, a1);
        a1 = fmaf(f.z, w1.z, a1); a1 = fmaf(f.w, w1.w, a1);
        a2 = fmaf(f.x, w2.x, a2); a2 = fmaf(f.y, w2.y, a2);
        a2 = fmaf(f.z, w2.z, a2); a2 = fmaf(f.w, w2.w, a2);
        a3 = fmaf(f.x, w3.x, a3); a3 = fmaf(f.y, w3.y, a3);
        a3 = fmaf(f.z, w3.z, a3); a3 = fmaf(f.w, w3.w, a3);
        a4 = fmaf(f.x, w4.x, a4); a4 = fmaf(f.y, w4.y, a4);
        a4 = fmaf(f.z, w4.z, a4); a4 = fmaf(f.w, w4.w, a4);
        a5 = fmaf(f.x, w5.x, a5); a5 = fmaf(f.y, w5.y, a5);
        a5 = fmaf(f.z, w5.z, a5); a5 = fmaf(f.w, w5.w, a5);
    }

    float* o = (kh ? xgp1 : xgp0) +
               ((size_t)dir * BB * SS + p0 + lane) * G4 + j0;
    ((float2*)o)[0] = make_float2(a0, a1);
    ((float2*)o)[1] = make_float2(a2, a3);
    ((float2*)o)[2] = make_float2(a4, a5);
}

// -------------------------------------------------------------------------
// Kernel 2 (v10): LSTM recurrence, gate-lane + DPP; NO ds_write in loop.
// Staging combines the two K-partials + bias + +-log2e prescale, reversed
// rows for bwd. Loop LDS ops = prefetch ds_reads ONLY (clean lgkmcnt);
// h stores go straight to global (6 lanes = 24B coalesced, fire-and-forget).
// -------------------------------------------------------------------------
__global__ __launch_bounds__(64) void k_lstm(
    const float* __restrict__ xgp0, const float* __restrict__ xgp1,
    const float* __restrict__ bfv, const float* __restrict__ bbv,
    const float* __restrict__ Whf, const float* __restrict__ Whb,
    float* __restrict__ repr)
{
    __shared__ float sxg[(SS + 8) * G4];    // 8 zero guard rows
    int blk = blockIdx.x;                   // 0..63
    int dir = blk >> 5;
    int b   = blk & 31;
    int lane = threadIdx.x;

    const float4* s0 = (const float4*)(xgp0 + ((size_t)dir * BB * SS + b * SS) * G4);
    const float4* s1 = (const float4*)(xgp1 + ((size_t)dir * BB * SS + b * SS) * G4);
    const float4* bias4 = (const float4*)(dir ? bbv : bfv);
    const float* Wh = dir ? Whb : Whf;

    // stage: combine partials + bias + prescale; reverse rows for bwd
    {
        float4* dst = (float4*)sxg;
        #pragma unroll
        for (int u = 0; u < 24; ++u) {
            int d = lane + u * 64;          // float4 index 0..1535
            int row = d / 6, c4 = d - row * 6;
            int drow = dir ? (SS - 1 - row) : row;
            float4 v0 = s0[d], v1 = s1[d], bv = bias4[c4];
            int cb = c4 * 4;
            float4 v;
            v.x = (v0.x + v1.x + bv.x) * ((cb + 0 >= 12 && cb + 0 < 18) ? 2.f * L2E : -L2E);
            v.y = (v0.y + v1.y + bv.y) * ((cb + 1 >= 12 && cb + 1 < 18) ? 2.f * L2E : -L2E);
            v.z = (v0.z + v1.z + bv.z) * ((cb + 2 >= 12 && cb + 2 < 18) ? 2.f * L2E : -L2E);
            v.w = (v0.w + v1.w + bv.w) * ((cb + 3 >= 12 && cb + 3 < 18) ? 2.f * L2E : -L2E);
            dst[drow * 6 + c4] = v;
        }
        for (int g2 = lane; g2 < 8 * G4; g2 += 64) sxg[SS * G4 + g2] = 0.f;
    }

    int g    = lane % G4;                   // gate slot 0..23
    int cell = g >> 2;                      // 0..5
    int type = g & 3;                       // 0=i 1=f 2=c 3=o
    int j    = type * HH + cell;            // keras column

    float kk = (type == 2) ? 2.f * L2E : -L2E;
    float wh[HH];
    #pragma unroll
    for (int m = 0; m < HH; ++m) wh[m] = Wh[m * G4 + j] * kk;
    float Bc = (type == 2) ? 1.f : 0.f;
    float Ac = (type == 2) ? -1.f : 1.f;

    float sh[HH];
    #pragma unroll
    for (int m = 0; m < HH; ++m) sh[m] = 0.f;
    float c = 0.f;
    bool wr = (lane < G4) && ((lane & 3) == 0);
    __syncthreads();

    const float* xb = sxg + j;
    // h store base: step s writes repr[(b*SS+s)*12 + dir*6 + cell]
    float* rb = repr + (size_t)b * SS * (2 * HH) + dir * HH + cell;

    float pg[4];
    #pragma unroll
    for (int sl = 0; sl < 4; ++sl) pg[sl] = xb[sl * G4];

    #pragma unroll 1
    for (int t = 0; t < SS; t += 4) {
        #pragma unroll
        for (int sl = 0; sl < 4; ++sl) {
            float x = pg[sl];
            pg[sl] = xb[(t + 4 + sl) * G4];      // guard rows cover the tail

            float aa  = fmaf(sh[1], wh[1], fmaf(sh[0], wh[0], x));
            float bb2 = fmaf(sh[3], wh[3], sh[2] * wh[2]);
            float cc2 = fmaf(sh[5], wh[5], sh[4] * wh[4]);
            x = (aa + bb2) + cc2;

            float e   = __builtin_amdgcn_exp2f(x);
            float val = fmaf(Bc, e, Ac) * fast_rcp(1.f + e);

            float vi = quad_bcast<0>(val);
            float vf = quad_bcast<85>(val);
            float vc = quad_bcast<170>(val);
            float vo = quad_bcast<255>(val);

            c = fmaf(vf, c, vi * vc);
            float ec = __builtin_amdgcn_exp2f(c * (2.f * L2E));
            float h  = (ec - 1.f) * fast_rcp(ec + 1.f) * vo;

            int tt = t + sl;
            int s  = dir ? (SS - 1 - tt) : tt;
            if (wr) rb[(size_t)s * (2 * HH)] = h;   // global, fire-and-forget
            #pragma unroll
            for (int m = 0; m < HH; ++m) sh[m] = bcast_lane(h, 4 * m);
        }
    }
}

// -------------------------------------------------------------------------
// Kernel 3: ua = repr@Wu+bu ; wa = repr@Ww+bw. One thread per (b,s).
// -------------------------------------------------------------------------
__global__ __launch_bounds__(256) void k_uawa(
    const float* __restrict__ repr,
    const float* __restrict__ Wu, const float* __restrict__ bu,
    const float* __restrict__ Ww, const float* __restrict__ bw,
    float* __restrict__ ua, float* __restrict__ wa)
{
    int bs = blockIdx.x * blockDim.x + threadIdx.x;   // 0..8191
    float r[AA];
    #pragma unroll
    for (int e = 0; e < AA; ++e) r[e] = repr[(size_t)bs * AA + e];
    #pragma unroll
    for (int d = 0; d < AA; ++d) {
        float au = bu[d], aw = bw[d];
        #pragma unroll
        for (int e = 0; e < AA; ++e) {
            au = fmaf(r[e], Wu[e * AA + d], au);
            aw = fmaf(r[e], Ww[e * AA + d], aw);
        }
        ua[(size_t)bs * AA + d] = au;
        wa[(size_t)bs * AA + d] = aw;
    }
}

// -------------------------------------------------------------------------
// Kernel 4: arc scores + sum-exp + CE partials + exp table.
// -------------------------------------------------------------------------
__global__ __launch_bounds__(256) void k_score(
    const float* __restrict__ ua, const float* __restrict__ wa,
    const float* __restrict__ v, const int* __restrict__ heads,
    float* __restrict__ out, float* __restrict__ ce)
{
    int bi = blockIdx.x;            // b*S + i
    int i  = bi & 255;
    int j  = threadIdx.x;

    __shared__ float swa[AA], sv[AA];
    if (j < AA) { swa[j] = wa[(size_t)bi * AA + j]; sv[j] = v[j]; }
    __syncthreads();

    const float* uj = ua + ((size_t)(bi & ~255) + j) * AA;
    float s = 0.f;
    #pragma unroll
    for (int d = 0; d < AA; ++d) s = fmaf(sv[d], fast_tanh(uj[d] + swa[d]), s);
    if (j == i) s = -10000.f;

    float e = __expf(s);
    if (i >= 1)
        out[1 + (((size_t)(i - 1) * BB + (bi >> 8)) * SS + j)] = e;

    float r = e;
    #pragma unroll
    for (int off = 32; off > 0; off >>= 1) r += __shfl_xor(r, off, 64);
    __shared__ float part[4];
    if ((j & 63) == 0) part[j >> 6] = r;
    __syncthreads();
    float tot = part[0] + part[1] + part[2] + part[3];

    if (j == heads[bi])
        ce[bi] = (i >= 1) ? (__logf(tot) - s) : 0.f;
}

// -------------------------------------------------------------------------
// Kernel 5: deterministic loss reduction: sum(ce)/B into out[0].
// -------------------------------------------------------------------------
__global__ __launch_bounds__(256) void k_loss(const float* __restrict__ ce,
                                              float* __restrict__ out)
{
    __shared__ float red[256];
    int t = threadIdx.x;
    float a = 0.f;
    for (int k = t; k < BB * SS; k += 256) a += ce[k];
    red[t] = a; __syncthreads();
    for (int off = 128; off > 0; off >>= 1) {
        if (t < off) red[t] += red[t + off];
        __syncthreads();
    }
    if (t == 0) out[0] = red[0] * (1.f / BB);
}

extern "C" void kernel_launch(void* const* d_in, const int* in_sizes, int n_in,
                              void* d_out, int out_size, void* d_ws, size_t ws_size,
                              hipStream_t stream)
{
    const int*   words = (const int*)  d_in[0];
    const int*   pos   = (const int*)  d_in[1];
    const float* morph = (const float*)d_in[2];
    const int*   heads = (const int*)  d_in[3];
    const float* wtab  = (const float*)d_in[4];
    const float* ptab  = (const float*)d_in[5];
    const float* Wxf   = (const float*)d_in[6];
    const float* Whf   = (const float*)d_in[7];
    const float* bf    = (const float*)d_in[8];
    const float* Wxb   = (const float*)d_in[9];
    const float* Whb   = (const float*)d_in[10];
    const float* bb    = (const float*)d_in[11];
    const float* Wu    = (const float*)d_in[12];
    const float* bu    = (const float*)d_in[13];
    const float* Ww    = (const float*)d_in[14];
    const float* bw    = (const float*)d_in[15];
    const float* v     = (const float*)d_in[16];
    float* out = (float*)d_out;

    // workspace layout (floats)
    float* xgp0 = (float*)d_ws;                  // 2*8192*24 (partial K 0-199)
    float* xgp1 = xgp0 + (size_t)2*BB*SS*G4;     // 2*8192*24 (partial K 200-399)
    float* WT   = xgp1 + (size_t)2*BB*SS*G4;     // 2*24*400
    float* repr = WT   + (size_t)2*G4*400;       // 8192*12
    float* ua   = repr + (size_t)BB*SS*2*HH;     // 8192*12
    float* wa   = ua   + (size_t)BB*SS*AA;       // 8192*12
    float* ce   = wa   + (size_t)BB*SS*AA;       // 8192

    k_wtprep<<<2, 256, 0, stream>>>(Wxf, Wxb, WT);
    k_xg<<<256, 512, 0, stream>>>(words, pos, morph, wtab, ptab, WT, xgp0, xgp1);
    k_lstm<<<BB * 2, 64, 0, stream>>>(xgp0, xgp1, bf, bb, Whf, Whb, repr);
    k_uawa<<<(BB * SS) / 256, 256, 0, stream>>>(repr, Wu, bu, Ww, bw, ua, wa);
    k_score<<<BB * SS, 256, 0, stream>>>(ua, wa, v, heads, out, ce);
    k_loss<<<1, 256, 0, stream>>>(ce, out);
}